// Round 1
// baseline (1859.072 us; speedup 1.0000x reference)
//
#include <hip/hip_runtime.h>

#define D 128
#define BN_EPS 1e-5f

// ---------------------------------------------------------------------------
// Edge dtype sniffer: reference declares int64 edge_index, but JAX without
// x64 produces int32. Values are in [0, N) (non-negative), so if the buffer
// is int64 every odd dword (high word) is 0. Check 16 odd dwords.
// ---------------------------------------------------------------------------
__global__ void k_detect(const int* __restrict__ ei, int* __restrict__ flag) {
  if (blockIdx.x == 0 && threadIdx.x == 0) {
    int is64 = 1;
    for (int i = 0; i < 16; i++)
      if (ei[2 * i + 1] != 0) is64 = 0;
    *flag = is64;
  }
}

__device__ __forceinline__ int load_src(const int* ei, int e, int i, int is64) {
  return is64 ? ei[2 * i] : ei[i];
}
__device__ __forceinline__ int load_dst(const int* ei, int e, int i, int is64) {
  return is64 ? ei[2 * e + 2 * i] : ei[e + i];
}

// ---------------------------------------------------------------------------
// Graph prep: histogram of incoming-edge counts per dst node
// ---------------------------------------------------------------------------
__global__ void k_hist(const int* __restrict__ ei, int* __restrict__ cnt,
                       const int* __restrict__ flag, int e) {
  int i = blockIdx.x * blockDim.x + threadIdx.x;
  if (i < e) {
    int d = load_dst(ei, e, i, *flag);
    atomicAdd(&cnt[d], 1);
  }
}

// Block-level exclusive scan (1024 elements per block of 256 threads)
__global__ void k_scan1(const int* __restrict__ cnt, int* __restrict__ excl,
                        int* __restrict__ bsum, int n) {
  __shared__ int s[256];
  int t = threadIdx.x;
  int base = blockIdx.x * 1024;
  int v[4];
  int tot = 0;
#pragma unroll
  for (int i = 0; i < 4; i++) {
    int idx = base + t * 4 + i;
    v[i] = (idx < n) ? cnt[idx] : 0;
    tot += v[i];
  }
  s[t] = tot;
  __syncthreads();
#pragma unroll
  for (int off = 1; off < 256; off <<= 1) {
    int x = (t >= off) ? s[t - off] : 0;
    __syncthreads();
    s[t] += x;
    __syncthreads();
  }
  int run = s[t] - tot;  // exclusive prefix within block
#pragma unroll
  for (int i = 0; i < 4; i++) {
    int idx = base + t * 4 + i;
    if (idx < n) excl[idx] = run;
    run += v[i];
  }
  if (t == 255) bsum[blockIdx.x] = s[255];
}

__global__ void k_scan2(int* bsum, int nb) {
  if (blockIdx.x == 0 && threadIdx.x == 0) {
    int run = 0;
    for (int i = 0; i < nb; i++) {
      int t = bsum[i];
      bsum[i] = run;
      run += t;
    }
  }
}

__global__ void k_scan3(const int* __restrict__ excl, const int* __restrict__ bsum,
                        int* __restrict__ row_ptr, int n, int e) {
  int i = blockIdx.x * blockDim.x + threadIdx.x;
  if (i < n) row_ptr[i] = excl[i] + bsum[i >> 10];
  if (i == 0) row_ptr[n] = e;
}

__global__ void k_dinv(const int* __restrict__ cnt, float* __restrict__ dinv, int n) {
  int i = blockIdx.x * blockDim.x + threadIdx.x;
  if (i < n) dinv[i] = rsqrtf((float)(cnt[i] + 1));  // +1 = self loop
}

__global__ void k_scatter(const int* __restrict__ ei, const int* __restrict__ row_ptr,
                          int* __restrict__ fill, const float* __restrict__ dinv,
                          int* __restrict__ col, float* __restrict__ wgt,
                          const int* __restrict__ flag, int e) {
  int i = blockIdx.x * blockDim.x + threadIdx.x;
  if (i < e) {
    int is64 = *flag;
    int s = load_src(ei, e, i, is64);
    int d = load_dst(ei, e, i, is64);
    int pos = row_ptr[d] + atomicAdd(&fill[d], 1);
    col[pos] = s;
    wgt[pos] = dinv[s] * dinv[d];
  }
}

// ---------------------------------------------------------------------------
// GEMM: C[n,128] = A[n,128] @ W[128,128], fp32, 128x128 tile per block.
// 16x16 thread grid, 8x8 register micro-tile per thread, A+W staged in LDS.
// ---------------------------------------------------------------------------
__global__ __launch_bounds__(256) void k_gemm(const float* __restrict__ A,
                                              const float* __restrict__ W,
                                              float* __restrict__ C, int n) {
  __shared__ float As[128 * 36];  // stride 36: float4-aligned, breaks worst banking
  __shared__ float Ws[32 * 128];
  const int t = threadIdx.x;
  const int ty = t >> 4, tx = t & 15;
  const int rowBase = blockIdx.x * 128;
  float acc[8][8];
#pragma unroll
  for (int i = 0; i < 8; i++)
#pragma unroll
    for (int j = 0; j < 8; j++) acc[i][j] = 0.f;

  for (int kc = 0; kc < 128; kc += 32) {
    __syncthreads();
#pragma unroll
    for (int i = 0; i < 4; i++) {
      int q = t + i * 256;
      int r = q >> 3;
      int kk = (q & 7) << 2;
      int gr = rowBase + r;
      if (gr >= n) gr = n - 1;  // clamp (garbage rows never stored)
      float4 v = *(const float4*)(A + (size_t)gr * 128 + kc + kk);
      *(float4*)(&As[r * 36 + kk]) = v;
    }
#pragma unroll
    for (int i = 0; i < 4; i++) {
      int q = t + i * 256;
      int k = q >> 5;
      int c = (q & 31) << 2;
      *(float4*)(&Ws[k * 128 + c]) = *(const float4*)(W + (size_t)(kc + k) * 128 + c);
    }
    __syncthreads();
#pragma unroll
    for (int k = 0; k < 32; k++) {
      float a[8];
#pragma unroll
      for (int i = 0; i < 8; i++) a[i] = As[(ty * 8 + i) * 36 + k];
      float4 w0 = *(float4*)(&Ws[k * 128 + tx * 8]);
      float4 w1 = *(float4*)(&Ws[k * 128 + tx * 8 + 4]);
      float w[8] = {w0.x, w0.y, w0.z, w0.w, w1.x, w1.y, w1.z, w1.w};
#pragma unroll
      for (int i = 0; i < 8; i++)
#pragma unroll
        for (int j = 0; j < 8; j++) acc[i][j] += a[i] * w[j];
    }
  }
#pragma unroll
  for (int i = 0; i < 8; i++) {
    int r = rowBase + ty * 8 + i;
    if (r < n) {
      float4 o0 = {acc[i][0], acc[i][1], acc[i][2], acc[i][3]};
      float4 o1 = {acc[i][4], acc[i][5], acc[i][6], acc[i][7]};
      *(float4*)(C + (size_t)r * 128 + tx * 8) = o0;
      *(float4*)(C + (size_t)r * 128 + tx * 8 + 4) = o1;
    }
  }
}

// ---------------------------------------------------------------------------
// Aggregation: out[n] = sum_{e in CSR[n]} wgt[e]*h[col[e]] + dinv[n]^2*h[n] + b
// One wave per node; lane l owns channels 2l, 2l+1 (float2 -> 512B/wave reads).
// Optionally accumulates per-channel sum/sumsq for BatchNorm (LDS partials,
// one global atomicAdd set per block).
// ---------------------------------------------------------------------------
__global__ __launch_bounds__(256) void k_agg(const float* __restrict__ h,
                                             const int* __restrict__ row_ptr,
                                             const int* __restrict__ col,
                                             const float* __restrict__ wgt,
                                             const float* __restrict__ dinv,
                                             const float* __restrict__ bias,
                                             float* __restrict__ out,
                                             float* __restrict__ stats, int n,
                                             int with_stats) {
  __shared__ float lsum[128], lsq[128];
  const int t = threadIdx.x;
  if (with_stats) {
    if (t < 128) {
      lsum[t] = 0.f;
      lsq[t] = 0.f;
    }
    __syncthreads();
  }
  const int wave = t >> 6, lane = t & 63;
  const int c0 = lane * 2;
  const float bx = bias[c0], by = bias[c0 + 1];
  for (int nd = blockIdx.x * 4 + wave; nd < n; nd += gridDim.x * 4) {
    float di = dinv[nd];
    float w0 = di * di;
    float2 hv = ((const float2*)(h + (size_t)nd * 128))[lane];
    float ax = w0 * hv.x, ay = w0 * hv.y;
    int e0 = row_ptr[nd], e1 = row_ptr[nd + 1];
    for (int e = e0; e < e1; e++) {
      int s = col[e];
      float w = wgt[e];
      float2 hs = ((const float2*)(h + (size_t)s * 128))[lane];
      ax += w * hs.x;
      ay += w * hs.y;
    }
    ax += bx;
    ay += by;
    float2 o = {ax, ay};
    ((float2*)(out + (size_t)nd * 128))[lane] = o;
    if (with_stats) {
      atomicAdd(&lsum[c0], ax);
      atomicAdd(&lsum[c0 + 1], ay);
      atomicAdd(&lsq[c0], ax * ax);
      atomicAdd(&lsq[c0 + 1], ay * ay);
    }
  }
  if (with_stats) {
    __syncthreads();
    if (t < 128) {
      atomicAdd(&stats[t], lsum[t]);
      atomicAdd(&stats[128 + t], lsq[t]);
    }
  }
}

// ---------------------------------------------------------------------------
// BatchNorm finalize: per-channel scale/shift from accumulated sum/sumsq
// ---------------------------------------------------------------------------
__global__ void k_bnfin(const float* __restrict__ stats, const float* __restrict__ gamma,
                        const float* __restrict__ beta, float* __restrict__ scsh, int n) {
  int c = threadIdx.x;
  if (c < 128) {
    float inv_n = 1.0f / (float)n;
    float mean = stats[c] * inv_n;
    float var = stats[128 + c] * inv_n - mean * mean;
    if (var < 0.f) var = 0.f;
    float is = rsqrtf(var + BN_EPS);
    float sc = gamma[c] * is;
    scsh[c] = sc;
    scsh[128 + c] = beta[c] - mean * sc;
  }
}

// ---------------------------------------------------------------------------
// BN apply + ReLU + optional residual: xout = relu(agg*sc+sh) (+ res)
// ---------------------------------------------------------------------------
__global__ __launch_bounds__(256) void k_apply(const float* __restrict__ agg,
                                               const float* __restrict__ res,
                                               const float* __restrict__ scsh,
                                               float* __restrict__ xout, int total) {
  int i = (blockIdx.x * 256 + threadIdx.x) * 4;
  if (i < total) {
    int c = i & 127;
    float4 v = *(const float4*)(agg + i);
    float4 sc = *(const float4*)(scsh + c);
    float4 sh = *(const float4*)(scsh + 128 + c);
    float4 r;
    r.x = fmaxf(v.x * sc.x + sh.x, 0.f);
    r.y = fmaxf(v.y * sc.y + sh.y, 0.f);
    r.z = fmaxf(v.z * sc.z + sh.z, 0.f);
    r.w = fmaxf(v.w * sc.w + sh.w, 0.f);
    if (res) {
      float4 rv = *(const float4*)(res + i);
      r.x += rv.x;
      r.y += rv.y;
      r.z += rv.z;
      r.w += rv.w;
    }
    *(float4*)(xout + i) = r;
  }
}

// ---------------------------------------------------------------------------
extern "C" void kernel_launch(void* const* d_in, const int* in_sizes, int n_in,
                              void* d_out, int out_size, void* d_ws, size_t ws_size,
                              hipStream_t stream) {
  const float* x_in = (const float*)d_in[0];
  const int* ei = (const int*)d_in[1];
  const float* W0 = (const float*)d_in[2];
  const float* b0 = (const float*)d_in[3];
  const float* Wmid = (const float*)d_in[4];
  const float* bmid = (const float*)d_in[5];
  const float* Wlast = (const float*)d_in[6];
  const float* blast = (const float*)d_in[7];
  const float* gamma = (const float*)d_in[8];
  const float* beta = (const float*)d_in[9];

  const int n = in_sizes[0] / D;  // 100000
  const int e = in_sizes[1] / 2;  // 1600000

  // ---- workspace carve-out (all 256B aligned) ----
  char* ws = (char*)d_ws;
  size_t off = 0;
  auto alloc = [&](size_t bytes) -> void* {
    void* p = ws + off;
    off += (bytes + 255) & ~(size_t)255;
    return p;
  };
  float* B0 = (float*)alloc((size_t)n * D * 4);
  float* B1 = (float*)alloc((size_t)n * D * 4);
  float* B2 = (float*)alloc((size_t)n * D * 4);
  int* col = (int*)alloc((size_t)e * 4);
  float* wgt = (float*)alloc((size_t)e * 4);
  int* row_ptr = (int*)alloc((size_t)(n + 1) * 4);
  int* excl = (int*)alloc((size_t)n * 4);
  float* dinv = (float*)alloc((size_t)n * 4);
  int* bsum = (int*)alloc(1024);
  float* scsh = (float*)alloc(5 * 256 * 4);
  int* flag = (int*)alloc(256);
  // zeroed region (single memset): cnt | fill | stats
  char* zbase = ws + off;
  int* cnt = (int*)alloc((size_t)n * 4);
  int* fill = (int*)alloc((size_t)n * 4);
  float* stats = (float*)alloc(5 * 256 * 4);
  size_t zbytes = (size_t)((ws + off) - zbase);
  hipMemsetAsync(zbase, 0, zbytes, stream);

  // ---- graph prep ----
  k_detect<<<1, 64, 0, stream>>>(ei, flag);
  int eb = (e + 255) / 256;
  k_hist<<<eb, 256, 0, stream>>>(ei, cnt, flag, e);
  int nb1024 = (n + 1023) / 1024;
  k_scan1<<<nb1024, 256, 0, stream>>>(cnt, excl, bsum, n);
  k_scan2<<<1, 64, 0, stream>>>(bsum, nb1024);
  int nb256 = (n + 255) / 256;
  k_scan3<<<nb256, 256, 0, stream>>>(excl, bsum, row_ptr, n, e);
  k_dinv<<<nb256, 256, 0, stream>>>(cnt, dinv, n);
  k_scatter<<<eb, 256, 0, stream>>>(ei, row_ptr, fill, dinv, col, wgt, flag, e);

  // ---- layers ----
  const int gemm_blocks = (n + 127) / 128;
  const int agg_blocks = 2048;
  const int apply_blocks = (n * D / 4 + 255) / 256;
  const int total = n * D;

  const float* xcur = x_in;
  float* hbuf = B0;  // gemm target; apply writes x_{i+1} over it
  float* other = B1;

  for (int L = 0; L < 5; L++) {
    const float* W = (L == 0) ? W0 : Wmid + (size_t)(L - 1) * D * D;
    const float* b = (L == 0) ? b0 : bmid + (size_t)(L - 1) * D;
    float* statsL = stats + L * 256;
    float* scshL = scsh + L * 256;
    k_gemm<<<gemm_blocks, 256, 0, stream>>>(xcur, W, hbuf, n);
    k_agg<<<agg_blocks, 256, 0, stream>>>(hbuf, row_ptr, col, wgt, dinv, b, B2,
                                          statsL, n, 1);
    k_bnfin<<<1, 128, 0, stream>>>(statsL, gamma + L * D, beta + L * D, scshL, n);
    k_apply<<<apply_blocks, 256, 0, stream>>>(B2, (L > 0) ? xcur : nullptr, scshL,
                                              hbuf, total);
    // rotate: new x = hbuf; next gemm writes into `other`
    xcur = hbuf;
    float* tmp = hbuf;
    hbuf = other;
    other = tmp;
    if (L == 0) other = B1 == hbuf ? B0 : B1;  // defensive (no-op with flow above)
  }
  // output layer: no BN/ReLU/residual, write straight to d_out
  k_gemm<<<gemm_blocks, 256, 0, stream>>>(xcur, Wlast, hbuf, n);
  k_agg<<<agg_blocks, 256, 0, stream>>>(hbuf, row_ptr, col, wgt, dinv, blast,
                                        (float*)d_out, nullptr, n, 0);
}

// Round 2
// 1553.323 us; speedup vs baseline: 1.1968x; 1.1968x over previous
//
#include <hip/hip_runtime.h>

#define D 128
#define BN_EPS 1e-5f

// ---------------- bf16 pack/unpack helpers ----------------
__device__ __forceinline__ unsigned int f2bf(float f) {
  unsigned int u = __float_as_uint(f);
  return (u + 0x7fffu + ((u >> 16) & 1u)) >> 16;  // RNE
}
__device__ __forceinline__ unsigned int packbf(float lo, float hi) {
  return f2bf(lo) | (f2bf(hi) << 16);
}
__device__ __forceinline__ float blo(unsigned int u) {
  return __uint_as_float(u << 16);
}
__device__ __forceinline__ float bhi(unsigned int u) {
  return __uint_as_float(u & 0xffff0000u);
}

// ---------------------------------------------------------------------------
// Edge dtype sniffer: reference declares int64 edge_index, but JAX without
// x64 produces int32. Values are in [0, N) (non-negative), so if the buffer
// is int64 every odd dword (high word) is 0. Check 16 odd dwords.
// ---------------------------------------------------------------------------
__global__ void k_detect(const int* __restrict__ ei, int* __restrict__ flag) {
  if (blockIdx.x == 0 && threadIdx.x == 0) {
    int is64 = 1;
    for (int i = 0; i < 16; i++)
      if (ei[2 * i + 1] != 0) is64 = 0;
    *flag = is64;
  }
}

__device__ __forceinline__ int load_src(const int* ei, int e, int i, int is64) {
  return is64 ? ei[2 * i] : ei[i];
}
__device__ __forceinline__ int load_dst(const int* ei, int e, int i, int is64) {
  return is64 ? ei[2 * e + 2 * i] : ei[e + i];
}

// ---------------------------------------------------------------------------
// Graph prep
// ---------------------------------------------------------------------------
__global__ void k_hist(const int* __restrict__ ei, int* __restrict__ cnt,
                       const int* __restrict__ flag, int e) {
  int i = blockIdx.x * blockDim.x + threadIdx.x;
  if (i < e) {
    int d = load_dst(ei, e, i, *flag);
    atomicAdd(&cnt[d], 1);
  }
}

__global__ void k_scan1(const int* __restrict__ cnt, int* __restrict__ excl,
                        int* __restrict__ bsum, int n) {
  __shared__ int s[256];
  int t = threadIdx.x;
  int base = blockIdx.x * 1024;
  int v[4];
  int tot = 0;
#pragma unroll
  for (int i = 0; i < 4; i++) {
    int idx = base + t * 4 + i;
    v[i] = (idx < n) ? cnt[idx] : 0;
    tot += v[i];
  }
  s[t] = tot;
  __syncthreads();
#pragma unroll
  for (int off = 1; off < 256; off <<= 1) {
    int x = (t >= off) ? s[t - off] : 0;
    __syncthreads();
    s[t] += x;
    __syncthreads();
  }
  int run = s[t] - tot;
#pragma unroll
  for (int i = 0; i < 4; i++) {
    int idx = base + t * 4 + i;
    if (idx < n) excl[idx] = run;
    run += v[i];
  }
  if (t == 255) bsum[blockIdx.x] = s[255];
}

__global__ void k_scan2(int* bsum, int nb) {
  if (blockIdx.x == 0 && threadIdx.x == 0) {
    int run = 0;
    for (int i = 0; i < nb; i++) {
      int t = bsum[i];
      bsum[i] = run;
      run += t;
    }
  }
}

__global__ void k_scan3(const int* __restrict__ excl, const int* __restrict__ bsum,
                        int* __restrict__ row_ptr, int n, int e) {
  int i = blockIdx.x * blockDim.x + threadIdx.x;
  if (i < n) row_ptr[i] = excl[i] + bsum[i >> 10];
  if (i == 0) row_ptr[n] = e;
}

__global__ void k_dinv(const int* __restrict__ cnt, float* __restrict__ dinv, int n) {
  int i = blockIdx.x * blockDim.x + threadIdx.x;
  if (i < n) dinv[i] = rsqrtf((float)(cnt[i] + 1));
}

__global__ void k_scatter(const int* __restrict__ ei, const int* __restrict__ row_ptr,
                          int* __restrict__ fill, const float* __restrict__ dinv,
                          int* __restrict__ col, float* __restrict__ wgt,
                          const int* __restrict__ flag, int e) {
  int i = blockIdx.x * blockDim.x + threadIdx.x;
  if (i < e) {
    int is64 = *flag;
    int s = load_src(ei, e, i, is64);
    int d = load_dst(ei, e, i, is64);
    int pos = row_ptr[d] + atomicAdd(&fill[d], 1);
    col[pos] = s;
    wgt[pos] = dinv[s] * dinv[d];
  }
}

// ---------------------------------------------------------------------------
// GEMM: H[n,128] = A[n,128] @ W[128,128], fp32 math, bf16-packed output.
// 128x128 tile per block, 16x16 threads, 8x8 register micro-tile.
// ---------------------------------------------------------------------------
__global__ __launch_bounds__(256) void k_gemm(const float* __restrict__ A,
                                              const float* __restrict__ W,
                                              unsigned int* __restrict__ Hb, int n) {
  __shared__ float As[128 * 36];
  __shared__ float Ws[32 * 128];
  const int t = threadIdx.x;
  const int ty = t >> 4, tx = t & 15;
  const int rowBase = blockIdx.x * 128;
  float acc[8][8];
#pragma unroll
  for (int i = 0; i < 8; i++)
#pragma unroll
    for (int j = 0; j < 8; j++) acc[i][j] = 0.f;

  for (int kc = 0; kc < 128; kc += 32) {
    __syncthreads();
#pragma unroll
    for (int i = 0; i < 4; i++) {
      int q = t + i * 256;
      int r = q >> 3;
      int kk = (q & 7) << 2;
      int gr = rowBase + r;
      if (gr >= n) gr = n - 1;
      float4 v = *(const float4*)(A + (size_t)gr * 128 + kc + kk);
      *(float4*)(&As[r * 36 + kk]) = v;
    }
#pragma unroll
    for (int i = 0; i < 4; i++) {
      int q = t + i * 256;
      int k = q >> 5;
      int c = (q & 31) << 2;
      *(float4*)(&Ws[k * 128 + c]) = *(const float4*)(W + (size_t)(kc + k) * 128 + c);
    }
    __syncthreads();
#pragma unroll
    for (int k = 0; k < 32; k++) {
      float a[8];
#pragma unroll
      for (int i = 0; i < 8; i++) a[i] = As[(ty * 8 + i) * 36 + k];
      float4 w0 = *(float4*)(&Ws[k * 128 + tx * 8]);
      float4 w1 = *(float4*)(&Ws[k * 128 + tx * 8 + 4]);
      float w[8] = {w0.x, w0.y, w0.z, w0.w, w1.x, w1.y, w1.z, w1.w};
#pragma unroll
      for (int i = 0; i < 8; i++)
#pragma unroll
        for (int j = 0; j < 8; j++) acc[i][j] += a[i] * w[j];
    }
  }
#pragma unroll
  for (int i = 0; i < 8; i++) {
    int r = rowBase + ty * 8 + i;
    if (r < n) {
      uint4 p;
      p.x = packbf(acc[i][0], acc[i][1]);
      p.y = packbf(acc[i][2], acc[i][3]);
      p.z = packbf(acc[i][4], acc[i][5]);
      p.w = packbf(acc[i][6], acc[i][7]);
      *(uint4*)(Hb + (size_t)r * 64 + tx * 4) = p;
    }
  }
}

// ---------------------------------------------------------------------------
// Aggregation over bf16-packed h: one wave per node, lane l owns channels
// 2l,2l+1 (one packed uint -> 256B/wave/edge). Edge loop unrolled x4 so 4
// independent gathers are in flight per wave. col/wgt are wave-uniform
// (scalarized by compiler). fp32 accumulate + fp32 out (BN stats accuracy).
// ---------------------------------------------------------------------------
__global__ __launch_bounds__(256) void k_agg(const unsigned int* __restrict__ hb,
                                             const int* __restrict__ row_ptr,
                                             const int* __restrict__ col,
                                             const float* __restrict__ wgt,
                                             const float* __restrict__ dinv,
                                             const float* __restrict__ bias,
                                             float* __restrict__ out,
                                             float* __restrict__ stats, int n,
                                             int with_stats) {
  __shared__ float lsum[128], lsq[128];
  const int t = threadIdx.x;
  if (with_stats) {
    if (t < 128) {
      lsum[t] = 0.f;
      lsq[t] = 0.f;
    }
    __syncthreads();
  }
  const int wave = t >> 6, lane = t & 63;
  const int c0 = lane * 2;
  const float bx = bias[c0], by = bias[c0 + 1];
  for (int nd = blockIdx.x * 4 + wave; nd < n; nd += gridDim.x * 4) {
    float di = dinv[nd];
    float w0 = di * di;
    unsigned int hv = hb[(size_t)nd * 64 + lane];
    float ax = w0 * blo(hv), ay = w0 * bhi(hv);
    int e = row_ptr[nd], e1 = row_ptr[nd + 1];
    for (; e + 4 <= e1; e += 4) {
      int s0 = col[e], s1 = col[e + 1], s2 = col[e + 2], s3 = col[e + 3];
      float wa = wgt[e], wb = wgt[e + 1], wc = wgt[e + 2], wd = wgt[e + 3];
      unsigned int u0 = hb[(size_t)s0 * 64 + lane];
      unsigned int u1 = hb[(size_t)s1 * 64 + lane];
      unsigned int u2 = hb[(size_t)s2 * 64 + lane];
      unsigned int u3 = hb[(size_t)s3 * 64 + lane];
      ax += wa * blo(u0);
      ay += wa * bhi(u0);
      ax += wb * blo(u1);
      ay += wb * bhi(u1);
      ax += wc * blo(u2);
      ay += wc * bhi(u2);
      ax += wd * blo(u3);
      ay += wd * bhi(u3);
    }
    for (; e < e1; e++) {
      int s = col[e];
      float w = wgt[e];
      unsigned int u = hb[(size_t)s * 64 + lane];
      ax += w * blo(u);
      ay += w * bhi(u);
    }
    ax += bx;
    ay += by;
    float2 o = {ax, ay};
    ((float2*)(out + (size_t)nd * 128))[lane] = o;
    if (with_stats) {
      atomicAdd(&lsum[c0], ax);
      atomicAdd(&lsum[c0 + 1], ay);
      atomicAdd(&lsq[c0], ax * ax);
      atomicAdd(&lsq[c0 + 1], ay * ay);
    }
  }
  if (with_stats) {
    __syncthreads();
    if (t < 128) {
      atomicAdd(&stats[t], lsum[t]);
      atomicAdd(&stats[128 + t], lsq[t]);
    }
  }
}

// ---------------------------------------------------------------------------
__global__ void k_bnfin(const float* __restrict__ stats, const float* __restrict__ gamma,
                        const float* __restrict__ beta, float* __restrict__ scsh, int n) {
  int c = threadIdx.x;
  if (c < 128) {
    float inv_n = 1.0f / (float)n;
    float mean = stats[c] * inv_n;
    float var = stats[128 + c] * inv_n - mean * mean;
    if (var < 0.f) var = 0.f;
    float is = rsqrtf(var + BN_EPS);
    float sc = gamma[c] * is;
    scsh[c] = sc;
    scsh[128 + c] = beta[c] - mean * sc;
  }
}

// ---------------------------------------------------------------------------
// BN apply + ReLU + optional residual, IN PLACE over the agg buffer:
// buf = relu(buf*sc+sh) (+ res)
// ---------------------------------------------------------------------------
__global__ __launch_bounds__(256) void k_apply(float* __restrict__ buf,
                                               const float* __restrict__ res,
                                               const float* __restrict__ scsh,
                                               int total) {
  int i = (blockIdx.x * 256 + threadIdx.x) * 4;
  if (i < total) {
    int c = i & 127;
    float4 v = *(const float4*)(buf + i);
    float4 sc = *(const float4*)(scsh + c);
    float4 sh = *(const float4*)(scsh + 128 + c);
    float4 r;
    r.x = fmaxf(v.x * sc.x + sh.x, 0.f);
    r.y = fmaxf(v.y * sc.y + sh.y, 0.f);
    r.z = fmaxf(v.z * sc.z + sh.z, 0.f);
    r.w = fmaxf(v.w * sc.w + sh.w, 0.f);
    if (res) {
      float4 rv = *(const float4*)(res + i);
      r.x += rv.x;
      r.y += rv.y;
      r.z += rv.z;
      r.w += rv.w;
    }
    *(float4*)(buf + i) = r;
  }
}

// ---------------------------------------------------------------------------
extern "C" void kernel_launch(void* const* d_in, const int* in_sizes, int n_in,
                              void* d_out, int out_size, void* d_ws, size_t ws_size,
                              hipStream_t stream) {
  const float* x_in = (const float*)d_in[0];
  const int* ei = (const int*)d_in[1];
  const float* W0 = (const float*)d_in[2];
  const float* b0 = (const float*)d_in[3];
  const float* Wmid = (const float*)d_in[4];
  const float* bmid = (const float*)d_in[5];
  const float* Wlast = (const float*)d_in[6];
  const float* blast = (const float*)d_in[7];
  const float* gamma = (const float*)d_in[8];
  const float* beta = (const float*)d_in[9];

  const int n = in_sizes[0] / D;  // 100000
  const int e = in_sizes[1] / 2;  // 1600000

  // ---- workspace carve-out ----
  char* ws = (char*)d_ws;
  size_t off = 0;
  auto alloc = [&](size_t bytes) -> void* {
    void* p = ws + off;
    off += (bytes + 255) & ~(size_t)255;
    return p;
  };
  float* P0 = (float*)alloc((size_t)n * D * 4);          // fp32 node buffer
  float* P1 = (float*)alloc((size_t)n * D * 4);          // fp32 node buffer
  unsigned int* Hb = (unsigned int*)alloc((size_t)n * 64 * 4);  // bf16-packed h
  int* col = (int*)alloc((size_t)e * 4);
  float* wgt = (float*)alloc((size_t)e * 4);
  int* row_ptr = (int*)alloc((size_t)(n + 1) * 4);
  int* excl = (int*)alloc((size_t)n * 4);
  float* dinv = (float*)alloc((size_t)n * 4);
  int* bsum = (int*)alloc(1024);
  float* scsh = (float*)alloc(5 * 256 * 4);
  int* flag = (int*)alloc(256);
  // zeroed region: cnt | fill | stats
  char* zbase = ws + off;
  int* cnt = (int*)alloc((size_t)n * 4);
  int* fill = (int*)alloc((size_t)n * 4);
  float* stats = (float*)alloc(5 * 256 * 4);
  size_t zbytes = (size_t)((ws + off) - zbase);
  hipMemsetAsync(zbase, 0, zbytes, stream);

  // ---- graph prep ----
  k_detect<<<1, 64, 0, stream>>>(ei, flag);
  int eb = (e + 255) / 256;
  k_hist<<<eb, 256, 0, stream>>>(ei, cnt, flag, e);
  int nb1024 = (n + 1023) / 1024;
  k_scan1<<<nb1024, 256, 0, stream>>>(cnt, excl, bsum, n);
  k_scan2<<<1, 64, 0, stream>>>(bsum, nb1024);
  int nb256 = (n + 255) / 256;
  k_scan3<<<nb256, 256, 0, stream>>>(excl, bsum, row_ptr, n, e);
  k_dinv<<<nb256, 256, 0, stream>>>(cnt, dinv, n);
  k_scatter<<<eb, 256, 0, stream>>>(ei, row_ptr, fill, dinv, col, wgt, flag, e);

  // ---- layers ----
  const int gemm_blocks = (n + 127) / 128;
  const int agg_blocks = 2048;
  const int apply_blocks = (n * D / 4 + 255) / 256;
  const int total = n * D;

  const float* xcur = x_in;   // fp32 input to current layer's GEMM / residual
  float* tgt = P0;            // agg output + in-place apply target this layer

  for (int L = 0; L < 5; L++) {
    const float* W = (L == 0) ? W0 : Wmid + (size_t)(L - 1) * D * D;
    const float* b = (L == 0) ? b0 : bmid + (size_t)(L - 1) * D;
    float* statsL = stats + L * 256;
    float* scshL = scsh + L * 256;
    k_gemm<<<gemm_blocks, 256, 0, stream>>>(xcur, W, Hb, n);
    k_agg<<<agg_blocks, 256, 0, stream>>>(Hb, row_ptr, col, wgt, dinv, b, tgt,
                                          statsL, n, 1);
    k_bnfin<<<1, 128, 0, stream>>>(statsL, gamma + L * D, beta + L * D, scshL, n);
    k_apply<<<apply_blocks, 256, 0, stream>>>(tgt, (L > 0) ? xcur : nullptr, scshL,
                                              total);
    xcur = tgt;                       // new x
    tgt = (tgt == P0) ? P1 : P0;      // other buffer is now free
  }
  // output layer: no BN/ReLU/residual, write straight to d_out
  k_gemm<<<gemm_blocks, 256, 0, stream>>>(xcur, Wlast, Hb, n);
  k_agg<<<agg_blocks, 256, 0, stream>>>(Hb, row_ptr, col, wgt, dinv, blast,
                                        (float*)d_out, nullptr, n, 0);
}

// Round 3
// 1428.725 us; speedup vs baseline: 1.3012x; 1.0872x over previous
//
#include <hip/hip_runtime.h>

#define D 128
#define BN_EPS 1e-5f

typedef _Float16 half8 __attribute__((ext_vector_type(8)));
typedef float f32x4 __attribute__((ext_vector_type(4)));
typedef unsigned short ushort_t;

// ---------------- fp16 pack/unpack helpers ----------------
__device__ __forceinline__ unsigned short f2h(float f) {
  union { _Float16 h; unsigned short u; } c;
  c.h = (_Float16)f;  // RNE
  return c.u;
}
__device__ __forceinline__ unsigned int packh(float lo, float hi) {
  return (unsigned int)f2h(lo) | ((unsigned int)f2h(hi) << 16);
}
__device__ __forceinline__ float h2f(unsigned int v) {
  union { unsigned short u; _Float16 h; } c;
  c.u = (unsigned short)v;
  return (float)c.h;
}

// ---------------------------------------------------------------------------
// Edge dtype sniffer (int64 vs int32 edge_index)
// ---------------------------------------------------------------------------
__global__ void k_detect(const int* __restrict__ ei, int* __restrict__ flag) {
  if (blockIdx.x == 0 && threadIdx.x == 0) {
    int is64 = 1;
    for (int i = 0; i < 16; i++)
      if (ei[2 * i + 1] != 0) is64 = 0;
    *flag = is64;
  }
}
__device__ __forceinline__ int load_src(const int* ei, int e, int i, int is64) {
  return is64 ? ei[2 * i] : ei[i];
}
__device__ __forceinline__ int load_dst(const int* ei, int e, int i, int is64) {
  return is64 ? ei[2 * e + 2 * i] : ei[e + i];
}

// ---------------------------------------------------------------------------
// Graph prep
// ---------------------------------------------------------------------------
__global__ void k_hist(const int* __restrict__ ei, int* __restrict__ cnt,
                       const int* __restrict__ flag, int e) {
  int i = blockIdx.x * blockDim.x + threadIdx.x;
  if (i < e) {
    int d = load_dst(ei, e, i, *flag);
    atomicAdd(&cnt[d], 1);
  }
}

__global__ void k_scan1(const int* __restrict__ cnt, int* __restrict__ excl,
                        int* __restrict__ bsum, int n) {
  __shared__ int s[256];
  int t = threadIdx.x;
  int base = blockIdx.x * 1024;
  int v[4];
  int tot = 0;
#pragma unroll
  for (int i = 0; i < 4; i++) {
    int idx = base + t * 4 + i;
    v[i] = (idx < n) ? cnt[idx] : 0;
    tot += v[i];
  }
  s[t] = tot;
  __syncthreads();
#pragma unroll
  for (int off = 1; off < 256; off <<= 1) {
    int x = (t >= off) ? s[t - off] : 0;
    __syncthreads();
    s[t] += x;
    __syncthreads();
  }
  int run = s[t] - tot;
#pragma unroll
  for (int i = 0; i < 4; i++) {
    int idx = base + t * 4 + i;
    if (idx < n) excl[idx] = run;
    run += v[i];
  }
  if (t == 255) bsum[blockIdx.x] = s[255];
}

__global__ void k_scan2(int* bsum, int nb) {
  if (blockIdx.x == 0 && threadIdx.x == 0) {
    int run = 0;
    for (int i = 0; i < nb; i++) {
      int t = bsum[i];
      bsum[i] = run;
      run += t;
    }
  }
}

__global__ void k_scan3(const int* __restrict__ excl, const int* __restrict__ bsum,
                        int* __restrict__ row_ptr, int n, int e) {
  int i = blockIdx.x * blockDim.x + threadIdx.x;
  if (i < n) row_ptr[i] = excl[i] + bsum[i >> 10];
  if (i == 0) row_ptr[n] = e;
}

__global__ void k_dinv(const int* __restrict__ cnt, float* __restrict__ dinv, int n) {
  int i = blockIdx.x * blockDim.x + threadIdx.x;
  if (i < n) dinv[i] = rsqrtf((float)(cnt[i] + 1));
}

__global__ void k_scatter(const int* __restrict__ ei, const int* __restrict__ row_ptr,
                          int* __restrict__ fill, const float* __restrict__ dinv,
                          int* __restrict__ col, float* __restrict__ wgt,
                          const int* __restrict__ flag, int e) {
  int i = blockIdx.x * blockDim.x + threadIdx.x;
  if (i < e) {
    int is64 = *flag;
    int s = load_src(ei, e, i, is64);
    int d = load_dst(ei, e, i, is64);
    int pos = row_ptr[d] + atomicAdd(&fill[d], 1);
    col[pos] = s;
    wgt[pos] = dinv[s] * dinv[d];
  }
}

// ---------------------------------------------------------------------------
// W fp32 -> fp16 in MFMA-B-fragment-major layout: Wf[l][(k>>3)*128 + c][k&7]
// ---------------------------------------------------------------------------
__global__ void k_wconv(const float* __restrict__ W0, const float* __restrict__ Wmid,
                        const float* __restrict__ Wlast, ushort_t* __restrict__ Wf) {
  int i = blockIdx.x * 256 + threadIdx.x;
  if (i >= 6 * 16384) return;
  int l = i >> 14, r = i & 16383;
  int k = r >> 7, c = r & 127;
  const float* W = (l == 0) ? W0 : (l <= 4 ? Wmid + (size_t)(l - 1) * 16384 : Wlast);
  Wf[(size_t)l * 16384 + (((k >> 3) * 128 + c) << 3) + (k & 7)] = f2h(W[r]);
}

// x fp32 -> fp16 packed
__global__ __launch_bounds__(256) void k_x2h(const float* __restrict__ x,
                                             unsigned int* __restrict__ Xh, int total) {
  int i = (blockIdx.x * 256 + threadIdx.x) * 4;
  if (i < total) {
    float4 v = *(const float4*)(x + i);
    uint2 p;
    p.x = packh(v.x, v.y);
    p.y = packh(v.z, v.w);
    *(uint2*)(Xh + (i >> 1)) = p;
  }
}

// ---------------------------------------------------------------------------
// MFMA GEMM: H[n,128] = X[n,128] @ W[128,128], fp16 in, fp32 acc, fp16 out.
// Block: 128 rows, 4 waves x 32 rows. A and W staged in LDS in fragment-major
// layout [k>>3][row][k&7] (16B-chunk permutation of row-major; conflict-free
// ds_read_b128, no padding). 64 mfma_f32_16x16x32_f16 per wave.
// ---------------------------------------------------------------------------
__global__ __launch_bounds__(256) void k_gemm(const ushort_t* __restrict__ Xh,
                                              const ushort_t* __restrict__ Wf,
                                              ushort_t* __restrict__ Hh, int n) {
  __shared__ ushort_t As[16384];  // 32 KB, frag-major
  __shared__ ushort_t Ws[16384];  // 32 KB, already frag-major in global
  const int t = threadIdx.x;
  const int rowBase = blockIdx.x * 128;
#pragma unroll
  for (int i = 0; i < 8; i++) {
    int c = t + i * 256;  // 16B chunk id, 0..2047
    int row = c >> 4, off = c & 15;
    int grow = rowBase + row;
    if (grow >= n) grow = n - 1;
    // global chunk (row, k=off*8..off*8+7) -> frag slot [off][row][0..7]
    *(uint4*)(&As[(off * 128 + row) * 8]) =
        *(const uint4*)(Xh + (size_t)grow * 128 + off * 8);
  }
#pragma unroll
  for (int i = 0; i < 8; i++) {
    int c = t + i * 256;
    *(uint4*)(&Ws[c * 8]) = *(const uint4*)(Wf + c * 8);
  }
  __syncthreads();

  const int wave = t >> 6, lane = t & 63;
  const int q = lane >> 4, ln = lane & 15;
  const int m0 = wave * 32;

  f32x4 acc[2][8];
#pragma unroll
  for (int mt = 0; mt < 2; mt++)
#pragma unroll
    for (int nt = 0; nt < 8; nt++) acc[mt][nt] = (f32x4){0.f, 0.f, 0.f, 0.f};

#pragma unroll
  for (int kk = 0; kk < 4; kk++) {
    int kg = kk * 4 + q;  // k-group = k>>3
    half8 a[2];
#pragma unroll
    for (int mt = 0; mt < 2; mt++)
      a[mt] = *(const half8*)(&As[(kg * 128 + m0 + mt * 16 + ln) * 8]);
    half8 b[8];
#pragma unroll
    for (int nt = 0; nt < 8; nt++)
      b[nt] = *(const half8*)(&Ws[(kg * 128 + nt * 16 + ln) * 8]);
#pragma unroll
    for (int mt = 0; mt < 2; mt++)
#pragma unroll
      for (int nt = 0; nt < 8; nt++)
        acc[mt][nt] =
            __builtin_amdgcn_mfma_f32_16x16x32_f16(a[mt], b[nt], acc[mt][nt], 0, 0, 0);
  }

  // epilogue: C/D layout col=lane&15, row=quad*4+reg
#pragma unroll
  for (int mt = 0; mt < 2; mt++) {
#pragma unroll
    for (int r = 0; r < 4; r++) {
      int grow = rowBase + m0 + mt * 16 + q * 4 + r;
      if (grow < n) {
#pragma unroll
        for (int nt = 0; nt < 8; nt++)
          Hh[(size_t)grow * 128 + nt * 16 + ln] = f2h(acc[mt][nt][r]);
      }
    }
  }
}

// ---------------------------------------------------------------------------
// Aggregation over fp16-packed h. Two nodes per wave (half-wave = 32 lanes,
// 4 channels/lane as uint2 -> 256B/edge). Per 32-edge chunk: col/wgt loaded
// coalesced into registers (lane l = edge l), distributed via __shfl
// (no memory dependency on the gather chain). Unroll 8, split accumulators:
// up to 16 gathers in flight per wave.
// ---------------------------------------------------------------------------
__global__ __launch_bounds__(256) void k_agg(const unsigned int* __restrict__ hb,
                                             const int* __restrict__ row_ptr,
                                             const int* __restrict__ col,
                                             const float* __restrict__ wgt,
                                             const float* __restrict__ dinv,
                                             const float* __restrict__ bias,
                                             float* __restrict__ out,
                                             float* __restrict__ stats, int n,
                                             int with_stats) {
  __shared__ float lsum[128], lsq[128];
  const int t = threadIdx.x;
  if (with_stats) {
    if (t < 128) {
      lsum[t] = 0.f;
      lsq[t] = 0.f;
    }
    __syncthreads();
  }
  const int hl = t & 31;      // lane within half-wave
  const int hbase = t & 32;   // shfl lane base of this half
  const int halfid = t >> 5;  // 0..7 per block
  const int c0 = hl * 4;
  float4 bv = *(const float4*)(bias + c0);

  for (int nd = blockIdx.x * 8 + halfid; nd < n; nd += gridDim.x * 8) {
    float di = dinv[nd];
    float w0 = di * di;
    uint2 hv = *(const uint2*)(hb + (size_t)nd * 64 + hl * 2);
    float p0 = w0 * h2f(hv.x & 0xffff), p1 = w0 * h2f(hv.x >> 16);
    float p2 = w0 * h2f(hv.y & 0xffff), p3 = w0 * h2f(hv.y >> 16);
    float q0 = 0.f, q1 = 0.f, q2 = 0.f, q3 = 0.f;
    int e0 = row_ptr[nd], e1 = row_ptr[nd + 1];
    int base = e0;
    while (base < e1) {
      int m = e1 - base;
      if (m > 32) m = 32;
      int cl = col[base + hl];      // coalesced; garbage if hl >= m (unused)
      float wl = wgt[base + hl];
      int j = 0;
      for (; j + 8 <= m; j += 8) {
        int s0 = __shfl(cl, hbase + j + 0), s1 = __shfl(cl, hbase + j + 1);
        int s2 = __shfl(cl, hbase + j + 2), s3 = __shfl(cl, hbase + j + 3);
        int s4 = __shfl(cl, hbase + j + 4), s5 = __shfl(cl, hbase + j + 5);
        int s6 = __shfl(cl, hbase + j + 6), s7 = __shfl(cl, hbase + j + 7);
        float wA = __shfl(wl, hbase + j + 0), wB = __shfl(wl, hbase + j + 1);
        float wC = __shfl(wl, hbase + j + 2), wD = __shfl(wl, hbase + j + 3);
        float wE = __shfl(wl, hbase + j + 4), wF = __shfl(wl, hbase + j + 5);
        float wG = __shfl(wl, hbase + j + 6), wH = __shfl(wl, hbase + j + 7);
        uint2 u0 = *(const uint2*)(hb + (size_t)s0 * 64 + hl * 2);
        uint2 u1 = *(const uint2*)(hb + (size_t)s1 * 64 + hl * 2);
        uint2 u2 = *(const uint2*)(hb + (size_t)s2 * 64 + hl * 2);
        uint2 u3 = *(const uint2*)(hb + (size_t)s3 * 64 + hl * 2);
        uint2 u4 = *(const uint2*)(hb + (size_t)s4 * 64 + hl * 2);
        uint2 u5 = *(const uint2*)(hb + (size_t)s5 * 64 + hl * 2);
        uint2 u6 = *(const uint2*)(hb + (size_t)s6 * 64 + hl * 2);
        uint2 u7 = *(const uint2*)(hb + (size_t)s7 * 64 + hl * 2);
        p0 += wA * h2f(u0.x & 0xffff); p1 += wA * h2f(u0.x >> 16);
        p2 += wA * h2f(u0.y & 0xffff); p3 += wA * h2f(u0.y >> 16);
        q0 += wB * h2f(u1.x & 0xffff); q1 += wB * h2f(u1.x >> 16);
        q2 += wB * h2f(u1.y & 0xffff); q3 += wB * h2f(u1.y >> 16);
        p0 += wC * h2f(u2.x & 0xffff); p1 += wC * h2f(u2.x >> 16);
        p2 += wC * h2f(u2.y & 0xffff); p3 += wC * h2f(u2.y >> 16);
        q0 += wD * h2f(u3.x & 0xffff); q1 += wD * h2f(u3.x >> 16);
        q2 += wD * h2f(u3.y & 0xffff); q3 += wD * h2f(u3.y >> 16);
        p0 += wE * h2f(u4.x & 0xffff); p1 += wE * h2f(u4.x >> 16);
        p2 += wE * h2f(u4.y & 0xffff); p3 += wE * h2f(u4.y >> 16);
        q0 += wF * h2f(u5.x & 0xffff); q1 += wF * h2f(u5.x >> 16);
        q2 += wF * h2f(u5.y & 0xffff); q3 += wF * h2f(u5.y >> 16);
        p0 += wG * h2f(u6.x & 0xffff); p1 += wG * h2f(u6.x >> 16);
        p2 += wG * h2f(u6.y & 0xffff); p3 += wG * h2f(u6.y >> 16);
        q0 += wH * h2f(u7.x & 0xffff); q1 += wH * h2f(u7.x >> 16);
        q2 += wH * h2f(u7.y & 0xffff); q3 += wH * h2f(u7.y >> 16);
      }
      for (; j < m; j++) {
        int s = __shfl(cl, hbase + j);
        float w = __shfl(wl, hbase + j);
        uint2 u = *(const uint2*)(hb + (size_t)s * 64 + hl * 2);
        p0 += w * h2f(u.x & 0xffff); p1 += w * h2f(u.x >> 16);
        p2 += w * h2f(u.y & 0xffff); p3 += w * h2f(u.y >> 16);
      }
      base += m;
    }
    float a0 = p0 + q0 + bv.x, a1 = p1 + q1 + bv.y;
    float a2 = p2 + q2 + bv.z, a3 = p3 + q3 + bv.w;
    float4 o = {a0, a1, a2, a3};
    *(float4*)(out + (size_t)nd * 128 + c0) = o;
    if (with_stats) {
      atomicAdd(&lsum[c0 + 0], a0);
      atomicAdd(&lsum[c0 + 1], a1);
      atomicAdd(&lsum[c0 + 2], a2);
      atomicAdd(&lsum[c0 + 3], a3);
      atomicAdd(&lsq[c0 + 0], a0 * a0);
      atomicAdd(&lsq[c0 + 1], a1 * a1);
      atomicAdd(&lsq[c0 + 2], a2 * a2);
      atomicAdd(&lsq[c0 + 3], a3 * a3);
    }
  }
  if (with_stats) {
    __syncthreads();
    if (t < 128) {
      atomicAdd(&stats[t], lsum[t]);
      atomicAdd(&stats[128 + t], lsq[t]);
    }
  }
}

// ---------------------------------------------------------------------------
__global__ void k_bnfin(const float* __restrict__ stats, const float* __restrict__ gamma,
                        const float* __restrict__ beta, float* __restrict__ scsh, int n) {
  int c = threadIdx.x;
  if (c < 128) {
    float inv_n = 1.0f / (float)n;
    float mean = stats[c] * inv_n;
    float var = stats[128 + c] * inv_n - mean * mean;
    if (var < 0.f) var = 0.f;
    float is = rsqrtf(var + BN_EPS);
    float sc = gamma[c] * is;
    scsh[c] = sc;
    scsh[128 + c] = beta[c] - mean * sc;
  }
}

// ---------------------------------------------------------------------------
// BN apply + ReLU + optional residual, in place over fp32 buf; also emits
// fp16-packed copy for the next layer's MFMA GEMM.
// ---------------------------------------------------------------------------
__global__ __launch_bounds__(256) void k_apply(float* __restrict__ buf,
                                               const float* __restrict__ res,
                                               const float* __restrict__ scsh,
                                               unsigned int* __restrict__ Xh,
                                               int total) {
  int i = (blockIdx.x * 256 + threadIdx.x) * 4;
  if (i < total) {
    int c = i & 127;
    float4 v = *(const float4*)(buf + i);
    float4 sc = *(const float4*)(scsh + c);
    float4 sh = *(const float4*)(scsh + 128 + c);
    float4 r;
    r.x = fmaxf(v.x * sc.x + sh.x, 0.f);
    r.y = fmaxf(v.y * sc.y + sh.y, 0.f);
    r.z = fmaxf(v.z * sc.z + sh.z, 0.f);
    r.w = fmaxf(v.w * sc.w + sh.w, 0.f);
    if (res) {
      float4 rv = *(const float4*)(res + i);
      r.x += rv.x;
      r.y += rv.y;
      r.z += rv.z;
      r.w += rv.w;
    }
    *(float4*)(buf + i) = r;
    uint2 p;
    p.x = packh(r.x, r.y);
    p.y = packh(r.z, r.w);
    *(uint2*)(Xh + (i >> 1)) = p;
  }
}

// ---------------------------------------------------------------------------
extern "C" void kernel_launch(void* const* d_in, const int* in_sizes, int n_in,
                              void* d_out, int out_size, void* d_ws, size_t ws_size,
                              hipStream_t stream) {
  const float* x_in = (const float*)d_in[0];
  const int* ei = (const int*)d_in[1];
  const float* W0 = (const float*)d_in[2];
  const float* b0 = (const float*)d_in[3];
  const float* Wmid = (const float*)d_in[4];
  const float* bmid = (const float*)d_in[5];
  const float* Wlast = (const float*)d_in[6];
  const float* blast = (const float*)d_in[7];
  const float* gamma = (const float*)d_in[8];
  const float* beta = (const float*)d_in[9];

  const int n = in_sizes[0] / D;  // 100000
  const int e = in_sizes[1] / 2;  // 1600000

  // ---- workspace carve-out ----
  char* ws = (char*)d_ws;
  size_t off = 0;
  auto alloc = [&](size_t bytes) -> void* {
    void* p = ws + off;
    off += (bytes + 255) & ~(size_t)255;
    return p;
  };
  float* P0 = (float*)alloc((size_t)n * D * 4);                  // fp32 node buf
  float* P1 = (float*)alloc((size_t)n * D * 4);                  // fp32 node buf
  unsigned int* Xh = (unsigned int*)alloc((size_t)n * 64 * 4);   // fp16 x
  unsigned int* Hh = (unsigned int*)alloc((size_t)n * 64 * 4);   // fp16 h
  ushort_t* Wf = (ushort_t*)alloc((size_t)6 * 16384 * 2);        // fp16 frag W
  int* col = (int*)alloc((size_t)e * 4);
  float* wgt = (float*)alloc((size_t)e * 4);
  int* row_ptr = (int*)alloc((size_t)(n + 1) * 4);
  int* excl = (int*)alloc((size_t)n * 4);
  float* dinv = (float*)alloc((size_t)n * 4);
  int* bsum = (int*)alloc(1024);
  float* scsh = (float*)alloc(5 * 256 * 4);
  int* flag = (int*)alloc(256);
  // zeroed region: cnt | fill | stats
  char* zbase = ws + off;
  int* cnt = (int*)alloc((size_t)n * 4);
  int* fill = (int*)alloc((size_t)n * 4);
  float* stats = (float*)alloc(5 * 256 * 4);
  size_t zbytes = (size_t)((ws + off) - zbase);
  hipMemsetAsync(zbase, 0, zbytes, stream);

  // ---- graph prep ----
  k_detect<<<1, 64, 0, stream>>>(ei, flag);
  int eb = (e + 255) / 256;
  k_hist<<<eb, 256, 0, stream>>>(ei, cnt, flag, e);
  int nb1024 = (n + 1023) / 1024;
  k_scan1<<<nb1024, 256, 0, stream>>>(cnt, excl, bsum, n);
  k_scan2<<<1, 64, 0, stream>>>(bsum, nb1024);
  int nb256 = (n + 255) / 256;
  k_scan3<<<nb256, 256, 0, stream>>>(excl, bsum, row_ptr, n, e);
  k_dinv<<<nb256, 256, 0, stream>>>(cnt, dinv, n);
  k_scatter<<<eb, 256, 0, stream>>>(ei, row_ptr, fill, dinv, col, wgt, flag, e);

  // ---- weight + input conversion ----
  k_wconv<<<(6 * 16384 + 255) / 256, 256, 0, stream>>>(W0, Wmid, Wlast, Wf);
  const int total = n * D;
  const int vec_blocks = (total / 4 + 255) / 256;
  k_x2h<<<vec_blocks, 256, 0, stream>>>(x_in, Xh, total);

  // ---- layers ----
  const int gemm_blocks = (n + 127) / 128;
  const int agg_blocks = 2048;

  const float* xcur = x_in;  // fp32 x of current layer (for residual)
  float* tgt = P0;           // agg output + in-place apply target

  for (int L = 0; L < 5; L++) {
    const float* b = (L == 0) ? b0 : bmid + (size_t)(L - 1) * D;
    float* statsL = stats + L * 256;
    float* scshL = scsh + L * 256;
    k_gemm<<<gemm_blocks, 256, 0, stream>>>((const ushort_t*)Xh,
                                            Wf + (size_t)L * 16384,
                                            (ushort_t*)Hh, n);
    k_agg<<<agg_blocks, 256, 0, stream>>>(Hh, row_ptr, col, wgt, dinv, b, tgt,
                                          statsL, n, 1);
    k_bnfin<<<1, 128, 0, stream>>>(statsL, gamma + L * D, beta + L * D, scshL, n);
    k_apply<<<vec_blocks, 256, 0, stream>>>(tgt, (L > 0) ? xcur : nullptr, scshL,
                                            Xh, total);
    xcur = tgt;
    tgt = (tgt == P0) ? P1 : P0;
  }
  // output layer: no BN/ReLU/residual, write straight to d_out
  k_gemm<<<gemm_blocks, 256, 0, stream>>>((const ushort_t*)Xh,
                                          Wf + (size_t)5 * 16384,
                                          (ushort_t*)Hh, n);
  k_agg<<<agg_blocks, 256, 0, stream>>>(Hh, row_ptr, col, wgt, dinv, blast,
                                        (float*)d_out, nullptr, n, 0);
}

// Round 4
// 1308.313 us; speedup vs baseline: 1.4210x; 1.0920x over previous
//
#include <hip/hip_runtime.h>

#define D 128
#define BN_EPS 1e-5f

typedef _Float16 half8 __attribute__((ext_vector_type(8)));
typedef float f32x4 __attribute__((ext_vector_type(4)));
typedef unsigned short ushort_t;

// ---------------- fp16 pack/unpack helpers ----------------
__device__ __forceinline__ unsigned short f2h(float f) {
  union { _Float16 h; unsigned short u; } c;
  c.h = (_Float16)f;  // RNE
  return c.u;
}
__device__ __forceinline__ unsigned int packh(float lo, float hi) {
  return (unsigned int)f2h(lo) | ((unsigned int)f2h(hi) << 16);
}
__device__ __forceinline__ float h2f(unsigned int v) {
  union { unsigned short u; _Float16 h; } c;
  c.u = (unsigned short)v;
  return (float)c.h;
}

// ---------------------------------------------------------------------------
// Edge dtype sniffer (int64 vs int32 edge_index)
// ---------------------------------------------------------------------------
__global__ void k_detect(const int* __restrict__ ei, int* __restrict__ flag) {
  if (blockIdx.x == 0 && threadIdx.x == 0) {
    int is64 = 1;
    for (int i = 0; i < 16; i++)
      if (ei[2 * i + 1] != 0) is64 = 0;
    *flag = is64;
  }
}
__device__ __forceinline__ int load_src(const int* ei, int e, int i, int is64) {
  return is64 ? ei[2 * i] : ei[i];
}
__device__ __forceinline__ int load_dst(const int* ei, int e, int i, int is64) {
  return is64 ? ei[2 * e + 2 * i] : ei[e + i];
}

// ---------------------------------------------------------------------------
// Graph prep. CSR rows are PADDED to a multiple of 8 (pad: col=0, wgt=0).
// ---------------------------------------------------------------------------
__global__ void k_hist(const int* __restrict__ ei, int* __restrict__ cnt,
                       const int* __restrict__ flag, int e) {
  int i = blockIdx.x * blockDim.x + threadIdx.x;
  if (i < e) {
    int d = load_dst(ei, e, i, *flag);
    atomicAdd(&cnt[d], 1);
  }
}

// scan over PADDED counts ((cnt+7)&~7)
__global__ void k_scan1(const int* __restrict__ cnt, int* __restrict__ excl,
                        int* __restrict__ bsum, int n) {
  __shared__ int s[256];
  int t = threadIdx.x;
  int base = blockIdx.x * 1024;
  int v[4];
  int tot = 0;
#pragma unroll
  for (int i = 0; i < 4; i++) {
    int idx = base + t * 4 + i;
    v[i] = (idx < n) ? ((cnt[idx] + 7) & ~7) : 0;
    tot += v[i];
  }
  s[t] = tot;
  __syncthreads();
#pragma unroll
  for (int off = 1; off < 256; off <<= 1) {
    int x = (t >= off) ? s[t - off] : 0;
    __syncthreads();
    s[t] += x;
    __syncthreads();
  }
  int run = s[t] - tot;
#pragma unroll
  for (int i = 0; i < 4; i++) {
    int idx = base + t * 4 + i;
    if (idx < n) excl[idx] = run;
    run += v[i];
  }
  if (t == 255) bsum[blockIdx.x] = s[255];
}

// also writes the padded grand total into row_ptr[n]
__global__ void k_scan2(int* bsum, int nb, int* row_ptr, int n) {
  if (blockIdx.x == 0 && threadIdx.x == 0) {
    int run = 0;
    for (int i = 0; i < nb; i++) {
      int t = bsum[i];
      bsum[i] = run;
      run += t;
    }
    row_ptr[n] = run;
  }
}

__global__ void k_scan3(const int* __restrict__ excl, const int* __restrict__ bsum,
                        int* __restrict__ row_ptr, int n) {
  int i = blockIdx.x * blockDim.x + threadIdx.x;
  if (i < n) row_ptr[i] = excl[i] + bsum[i >> 10];
}

__global__ void k_dinv(const int* __restrict__ cnt, float* __restrict__ dinv, int n) {
  int i = blockIdx.x * blockDim.x + threadIdx.x;
  if (i < n) dinv[i] = rsqrtf((float)(cnt[i] + 1));  // +1 self loop
}

__global__ void k_scatter(const int* __restrict__ ei, const int* __restrict__ row_ptr,
                          int* __restrict__ fill, const float* __restrict__ dinv,
                          int* __restrict__ col, float* __restrict__ wgt,
                          const int* __restrict__ flag, int e) {
  int i = blockIdx.x * blockDim.x + threadIdx.x;
  if (i < e) {
    int is64 = *flag;
    int s = load_src(ei, e, i, is64);
    int d = load_dst(ei, e, i, is64);
    int pos = row_ptr[d] + atomicAdd(&fill[d], 1);
    col[pos] = s;
    wgt[pos] = dinv[s] * dinv[d];
  }
}

// ---------------------------------------------------------------------------
// W fp32 -> fp16 in MFMA-B-fragment-major layout: Wf[l][(k>>3)*128 + c][k&7]
// ---------------------------------------------------------------------------
__global__ void k_wconv(const float* __restrict__ W0, const float* __restrict__ Wmid,
                        const float* __restrict__ Wlast, ushort_t* __restrict__ Wf) {
  int i = blockIdx.x * 256 + threadIdx.x;
  if (i >= 6 * 16384) return;
  int l = i >> 14, r = i & 16383;
  int k = r >> 7, c = r & 127;
  const float* W = (l == 0) ? W0 : (l <= 4 ? Wmid + (size_t)(l - 1) * 16384 : Wlast);
  Wf[(size_t)l * 16384 + (((k >> 3) * 128 + c) << 3) + (k & 7)] = f2h(W[r]);
}

// x fp32 -> fp16 packed
__global__ __launch_bounds__(256) void k_x2h(const float* __restrict__ x,
                                             unsigned int* __restrict__ Xh, int total) {
  int i = (blockIdx.x * 256 + threadIdx.x) * 4;
  if (i < total) {
    float4 v = *(const float4*)(x + i);
    uint2 p;
    p.x = packh(v.x, v.y);
    p.y = packh(v.z, v.w);
    *(uint2*)(Xh + (i >> 1)) = p;
  }
}

// ---------------------------------------------------------------------------
// MFMA GEMM: H[n,128] = X[n,128] @ W[128,128], fp16 in, fp32 acc, fp16 out.
// (unchanged from Round 3 — working well)
// ---------------------------------------------------------------------------
__global__ __launch_bounds__(256) void k_gemm(const ushort_t* __restrict__ Xh,
                                              const ushort_t* __restrict__ Wf,
                                              ushort_t* __restrict__ Hh, int n) {
  __shared__ ushort_t As[16384];
  __shared__ ushort_t Ws[16384];
  const int t = threadIdx.x;
  const int rowBase = blockIdx.x * 128;
#pragma unroll
  for (int i = 0; i < 8; i++) {
    int c = t + i * 256;
    int row = c >> 4, off = c & 15;
    int grow = rowBase + row;
    if (grow >= n) grow = n - 1;
    *(uint4*)(&As[(off * 128 + row) * 8]) =
        *(const uint4*)(Xh + (size_t)grow * 128 + off * 8);
  }
#pragma unroll
  for (int i = 0; i < 8; i++) {
    int c = t + i * 256;
    *(uint4*)(&Ws[c * 8]) = *(const uint4*)(Wf + c * 8);
  }
  __syncthreads();

  const int wave = t >> 6, lane = t & 63;
  const int q = lane >> 4, ln = lane & 15;
  const int m0 = wave * 32;

  f32x4 acc[2][8];
#pragma unroll
  for (int mt = 0; mt < 2; mt++)
#pragma unroll
    for (int nt = 0; nt < 8; nt++) acc[mt][nt] = (f32x4){0.f, 0.f, 0.f, 0.f};

#pragma unroll
  for (int kk = 0; kk < 4; kk++) {
    int kg = kk * 4 + q;
    half8 a[2];
#pragma unroll
    for (int mt = 0; mt < 2; mt++)
      a[mt] = *(const half8*)(&As[(kg * 128 + m0 + mt * 16 + ln) * 8]);
    half8 b[8];
#pragma unroll
    for (int nt = 0; nt < 8; nt++)
      b[nt] = *(const half8*)(&Ws[(kg * 128 + nt * 16 + ln) * 8]);
#pragma unroll
    for (int mt = 0; mt < 2; mt++)
#pragma unroll
      for (int nt = 0; nt < 8; nt++)
        acc[mt][nt] =
            __builtin_amdgcn_mfma_f32_16x16x32_f16(a[mt], b[nt], acc[mt][nt], 0, 0, 0);
  }

#pragma unroll
  for (int mt = 0; mt < 2; mt++) {
#pragma unroll
    for (int r = 0; r < 4; r++) {
      int grow = rowBase + m0 + mt * 16 + q * 4 + r;
      if (grow < n) {
#pragma unroll
        for (int nt = 0; nt < 8; nt++)
          Hh[(size_t)grow * 128 + nt * 16 + ln] = f2h(acc[mt][nt][r]);
      }
    }
  }
}

// ---------------------------------------------------------------------------
// Aggregation over fp16-packed h. One wave per node, lane = 2 channels
// (1 dword -> 256B/wave/edge). CSR rows padded to x8 -> branch-free unroll-8
// inner loop, 8 gathers in flight, next group's col/wgt prefetched (scalar)
// under the current group's gathers. Dual accumulators break FMA chains.
// ---------------------------------------------------------------------------
__global__ __launch_bounds__(256) void k_agg(const unsigned int* __restrict__ hb,
                                             const int* __restrict__ row_ptr,
                                             const int* __restrict__ col,
                                             const float* __restrict__ wgt,
                                             const float* __restrict__ dinv,
                                             const float* __restrict__ bias,
                                             float* __restrict__ out,
                                             float* __restrict__ stats, int n,
                                             int with_stats) {
  __shared__ float lsum[128], lsq[128];
  const int t = threadIdx.x;
  if (with_stats) {
    if (t < 128) {
      lsum[t] = 0.f;
      lsq[t] = 0.f;
    }
    __syncthreads();
  }
  const int wave = t >> 6, lane = t & 63;
  const int c0 = lane * 2;
  const float bx = bias[c0], by = bias[c0 + 1];

  for (int nd = blockIdx.x * 4 + wave; nd < n; nd += gridDim.x * 4) {
    float di = dinv[nd];
    float w0 = di * di;
    unsigned int hv = hb[(size_t)nd * 64 + lane];
    float ax0 = w0 * h2f(hv & 0xffff), ay0 = w0 * h2f(hv >> 16);
    float ax1 = 0.f, ay1 = 0.f;
    int e0 = row_ptr[nd], e1 = row_ptr[nd + 1];  // e1-e0 multiple of 8
    if (e0 < e1) {
      int sA[8];
      float wA[8];
#pragma unroll
      for (int j = 0; j < 8; j++) {
        sA[j] = col[e0 + j];
        wA[j] = wgt[e0 + j];
      }
      for (int e = e0; e < e1; e += 8) {
        int en = e + 8;
        int ep = (en < e1) ? en : e;  // clamp: reload current group if last
        int sB[8];
        float wB[8];
#pragma unroll
        for (int j = 0; j < 8; j++) {
          sB[j] = col[ep + j];
          wB[j] = wgt[ep + j];
        }
        unsigned int u[8];
#pragma unroll
        for (int j = 0; j < 8; j++) u[j] = hb[(size_t)sA[j] * 64 + lane];
#pragma unroll
        for (int j = 0; j < 8; j += 2) {
          ax0 += wA[j] * h2f(u[j] & 0xffff);
          ay0 += wA[j] * h2f(u[j] >> 16);
          ax1 += wA[j + 1] * h2f(u[j + 1] & 0xffff);
          ay1 += wA[j + 1] * h2f(u[j + 1] >> 16);
        }
#pragma unroll
        for (int j = 0; j < 8; j++) {
          sA[j] = sB[j];
          wA[j] = wB[j];
        }
      }
    }
    float a0 = ax0 + ax1 + bx, a1 = ay0 + ay1 + by;
    float2 o = {a0, a1};
    ((float2*)(out + (size_t)nd * 128))[lane] = o;
    if (with_stats) {
      atomicAdd(&lsum[c0], a0);
      atomicAdd(&lsum[c0 + 1], a1);
      atomicAdd(&lsq[c0], a0 * a0);
      atomicAdd(&lsq[c0 + 1], a1 * a1);
    }
  }
  if (with_stats) {
    __syncthreads();
    if (t < 128) {
      atomicAdd(&stats[t], lsum[t]);
      atomicAdd(&stats[128 + t], lsq[t]);
    }
  }
}

// ---------------------------------------------------------------------------
__global__ void k_bnfin(const float* __restrict__ stats, const float* __restrict__ gamma,
                        const float* __restrict__ beta, float* __restrict__ scsh, int n) {
  int c = threadIdx.x;
  if (c < 128) {
    float inv_n = 1.0f / (float)n;
    float mean = stats[c] * inv_n;
    float var = stats[128 + c] * inv_n - mean * mean;
    if (var < 0.f) var = 0.f;
    float is = rsqrtf(var + BN_EPS);
    float sc = gamma[c] * is;
    scsh[c] = sc;
    scsh[128 + c] = beta[c] - mean * sc;
  }
}

// ---------------------------------------------------------------------------
// BN apply + ReLU + optional residual, in place; also emits fp16 copy.
// ---------------------------------------------------------------------------
__global__ __launch_bounds__(256) void k_apply(float* __restrict__ buf,
                                               const float* __restrict__ res,
                                               const float* __restrict__ scsh,
                                               unsigned int* __restrict__ Xh,
                                               int total) {
  int i = (blockIdx.x * 256 + threadIdx.x) * 4;
  if (i < total) {
    int c = i & 127;
    float4 v = *(const float4*)(buf + i);
    float4 sc = *(const float4*)(scsh + c);
    float4 sh = *(const float4*)(scsh + 128 + c);
    float4 r;
    r.x = fmaxf(v.x * sc.x + sh.x, 0.f);
    r.y = fmaxf(v.y * sc.y + sh.y, 0.f);
    r.z = fmaxf(v.z * sc.z + sh.z, 0.f);
    r.w = fmaxf(v.w * sc.w + sh.w, 0.f);
    if (res) {
      float4 rv = *(const float4*)(res + i);
      r.x += rv.x;
      r.y += rv.y;
      r.z += rv.z;
      r.w += rv.w;
    }
    *(float4*)(buf + i) = r;
    uint2 p;
    p.x = packh(r.x, r.y);
    p.y = packh(r.z, r.w);
    *(uint2*)(Xh + (i >> 1)) = p;
  }
}

// ---------------------------------------------------------------------------
extern "C" void kernel_launch(void* const* d_in, const int* in_sizes, int n_in,
                              void* d_out, int out_size, void* d_ws, size_t ws_size,
                              hipStream_t stream) {
  const float* x_in = (const float*)d_in[0];
  const int* ei = (const int*)d_in[1];
  const float* W0 = (const float*)d_in[2];
  const float* b0 = (const float*)d_in[3];
  const float* Wmid = (const float*)d_in[4];
  const float* bmid = (const float*)d_in[5];
  const float* Wlast = (const float*)d_in[6];
  const float* blast = (const float*)d_in[7];
  const float* gamma = (const float*)d_in[8];
  const float* beta = (const float*)d_in[9];

  const int n = in_sizes[0] / D;  // 100000
  const int e = in_sizes[1] / 2;  // 1600000
  const int ec = e + 8 * n;       // padded-edge capacity

  // ---- workspace carve-out ----
  char* ws = (char*)d_ws;
  size_t off = 0;
  auto alloc = [&](size_t bytes) -> void* {
    void* p = ws + off;
    off += (bytes + 255) & ~(size_t)255;
    return p;
  };
  float* P0 = (float*)alloc((size_t)n * D * 4);
  float* P1 = (float*)alloc((size_t)n * D * 4);
  unsigned int* Xh = (unsigned int*)alloc((size_t)n * 64 * 4);
  unsigned int* Hh = (unsigned int*)alloc((size_t)n * 64 * 4);
  ushort_t* Wf = (ushort_t*)alloc((size_t)6 * 16384 * 2);
  int* row_ptr = (int*)alloc((size_t)(n + 1) * 4);
  int* excl = (int*)alloc((size_t)n * 4);
  float* dinv = (float*)alloc((size_t)n * 4);
  int* bsum = (int*)alloc(1024);
  float* scsh = (float*)alloc(5 * 256 * 4);
  int* flag = (int*)alloc(256);
  // zeroed region: col | wgt | cnt | fill | stats  (single memset)
  char* zbase = ws + off;
  int* col = (int*)alloc((size_t)ec * 4);
  float* wgt = (float*)alloc((size_t)ec * 4);
  int* cnt = (int*)alloc((size_t)n * 4);
  int* fill = (int*)alloc((size_t)n * 4);
  float* stats = (float*)alloc(5 * 256 * 4);
  size_t zbytes = (size_t)((ws + off) - zbase);
  hipMemsetAsync(zbase, 0, zbytes, stream);

  // ---- graph prep ----
  k_detect<<<1, 64, 0, stream>>>(ei, flag);
  int eb = (e + 255) / 256;
  k_hist<<<eb, 256, 0, stream>>>(ei, cnt, flag, e);
  int nb1024 = (n + 1023) / 1024;
  k_scan1<<<nb1024, 256, 0, stream>>>(cnt, excl, bsum, n);
  k_scan2<<<1, 64, 0, stream>>>(bsum, nb1024, row_ptr, n);
  int nb256 = (n + 255) / 256;
  k_scan3<<<nb256, 256, 0, stream>>>(excl, bsum, row_ptr, n);
  k_dinv<<<nb256, 256, 0, stream>>>(cnt, dinv, n);
  k_scatter<<<eb, 256, 0, stream>>>(ei, row_ptr, fill, dinv, col, wgt, flag, e);

  // ---- weight + input conversion ----
  k_wconv<<<(6 * 16384 + 255) / 256, 256, 0, stream>>>(W0, Wmid, Wlast, Wf);
  const int total = n * D;
  const int vec_blocks = (total / 4 + 255) / 256;
  k_x2h<<<vec_blocks, 256, 0, stream>>>(x_in, Xh, total);

  // ---- layers ----
  const int gemm_blocks = (n + 127) / 128;
  const int agg_blocks = 2048;

  const float* xcur = x_in;
  float* tgt = P0;

  for (int L = 0; L < 5; L++) {
    const float* b = (L == 0) ? b0 : bmid + (size_t)(L - 1) * D;
    float* statsL = stats + L * 256;
    float* scshL = scsh + L * 256;
    k_gemm<<<gemm_blocks, 256, 0, stream>>>((const ushort_t*)Xh,
                                            Wf + (size_t)L * 16384,
                                            (ushort_t*)Hh, n);
    k_agg<<<agg_blocks, 256, 0, stream>>>(Hh, row_ptr, col, wgt, dinv, b, tgt,
                                          statsL, n, 1);
    k_bnfin<<<1, 128, 0, stream>>>(statsL, gamma + L * D, beta + L * D, scshL, n);
    k_apply<<<vec_blocks, 256, 0, stream>>>(tgt, (L > 0) ? xcur : nullptr, scshL,
                                            Xh, total);
    xcur = tgt;
    tgt = (tgt == P0) ? P1 : P0;
  }
  k_gemm<<<gemm_blocks, 256, 0, stream>>>((const ushort_t*)Xh,
                                          Wf + (size_t)5 * 16384,
                                          (ushort_t*)Hh, n);
  k_agg<<<agg_blocks, 256, 0, stream>>>(Hh, row_ptr, col, wgt, dinv, blast,
                                        (float*)d_out, nullptr, n, 0);
}